// Round 1
// baseline (579.780 us; speedup 1.0000x reference)
//
#include <hip/hip_runtime.h>
#include <math.h>

#define BB   4
#define CC   64
#define HH   128
#define WW   128
#define COUT 64
#define HWs  (HH*WW)

// ws layout (bytes):
//   x_t : [B][H][W][C] f32 @ 0            (16,777,216)
//   om  : [B][27][H][W] f32 @ 16777216    ( 7,077,888)   ch 0..17 = offsets, 18..26 = sigmoid(mask)
//   w_t : [576][64]    f32 @ 23855104     (   147,456)   w_t[(k*64+c)*64+o] = w[o][c][k]

__global__ __launch_bounds__(256) void k_transpose_x(const float* __restrict__ x,
                                                     float* __restrict__ xt) {
    __shared__ float tile[64][65];
    int bid = blockIdx.x;
    int xs = (bid & 1) * 64;
    int y  = (bid >> 1) & 127;
    int b  = bid >> 8;
    int t = threadIdx.x;
    int lane = t & 63;
    int g = t >> 6;  // 0..3
#pragma unroll
    for (int i = 0; i < 16; ++i) {
        int c = i * 4 + g;
        tile[c][lane] = x[(((size_t)b*CC + c)*HH + y)*WW + xs + lane];
    }
    __syncthreads();
#pragma unroll
    for (int i = 0; i < 16; ++i) {
        int xx = i * 4 + g;
        xt[(((size_t)b*HH + y)*WW + xs + xx)*CC + lane] = tile[lane][xx];
    }
}

__global__ __launch_bounds__(256) void k_transpose_w(const float* __restrict__ w,
                                                     float* __restrict__ wt) {
    int d = blockIdx.x * 256 + threadIdx.x;   // 0..36863
    int o = d & 63;
    int c = (d >> 6) & 63;
    int k = d >> 12;                           // 0..8
    wt[d] = w[(o*CC + c)*9 + k];
}

__global__ __launch_bounds__(256) void k_conv_om(const float* __restrict__ x,
        const float* __restrict__ w_off, const float* __restrict__ b_off,
        const float* __restrict__ w_mask, const float* __restrict__ b_mask,
        float* __restrict__ om) {
    int idx = blockIdx.x * 256 + threadIdx.x;
    int xx = idx & 127;
    int y  = (idx >> 7) & 127;
    int ch = (idx >> 14) % 27;
    int b  = idx / (16384 * 27);

    const float* wp;
    float acc;
    if (ch < 18) { wp = w_off  + ch*CC*9;      acc = b_off[ch]; }
    else         { wp = w_mask + (ch-18)*CC*9; acc = b_mask[ch-18]; }

    const float* base = x + (size_t)b*CC*HWs + y*WW + xx;
    bool yl = y  > 0,  yh = y  < HH-1;
    bool xl = xx > 0,  xh = xx < WW-1;

    for (int c = 0; c < CC; ++c) {
        const float* p = base + c*HWs;
        const float* wq = wp + c*9;
        float v;
        v = (yl && xl) ? p[-WW-1] : 0.f;  acc += v * wq[0];
        v = (yl)       ? p[-WW]   : 0.f;  acc += v * wq[1];
        v = (yl && xh) ? p[-WW+1] : 0.f;  acc += v * wq[2];
        v = (xl)       ? p[-1]    : 0.f;  acc += v * wq[3];
        v =              p[0];            acc += v * wq[4];
        v = (xh)       ? p[1]     : 0.f;  acc += v * wq[5];
        v = (yh && xl) ? p[WW-1]  : 0.f;  acc += v * wq[6];
        v = (yh)       ? p[WW]    : 0.f;  acc += v * wq[7];
        v = (yh && xh) ? p[WW+1]  : 0.f;  acc += v * wq[8];
    }
    if (ch >= 18) acc = 1.f / (1.f + __expf(-acc));
    om[idx] = acc;
}

__global__ __launch_bounds__(256) void k_main(const float* __restrict__ xt,
        const float* __restrict__ om, const float* __restrict__ wt,
        const float* __restrict__ bias, float* __restrict__ out) {
    __shared__ __align__(16) float samp[16][580];
    int bid = blockIdx.x;
    int xs = (bid & 7) * 16;
    int y  = (bid >> 3) & 127;
    int b  = bid >> 10;
    int t = threadIdx.x;
    int lane = t & 63;       // = input channel c
    int wv   = t >> 6;       // wave 0..3

    // ---- phase 1: build sampled im2col tile (16 px x 576) in LDS ----
    const float* ombase = om + (size_t)b*27*HWs + y*WW;
    const float* xb = xt + (size_t)b*HWs*CC;
    for (int i = 0; i < 4; ++i) {
        int p  = wv*4 + i;
        int xx = xs + p;
#pragma unroll
        for (int k = 0; k < 9; ++k) {
            float dy = ombase[(2*k  )*HWs + xx];
            float dx = ombase[(2*k+1)*HWs + xx];
            float m  = ombase[(18+k )*HWs + xx];
            float sy = (float)(y  - 1 + k/3) + dy;
            float sx = (float)(xx - 1 + k%3) + dx;
            float fy = floorf(sy), fx = floorf(sx);
            float wy1 = sy - fy, wx1 = sx - fx;
            float wy0 = 1.f - wy1, wx0 = 1.f - wx1;
            int iy0 = (int)fy, ix0 = (int)fx;
            int iy1 = iy0 + 1, ix1 = ix0 + 1;
            bool y0ok = (iy0 >= 0) & (iy0 < HH);
            bool y1ok = (iy1 >= 0) & (iy1 < HH);
            bool x0ok = (ix0 >= 0) & (ix0 < WW);
            bool x1ok = (ix1 >= 0) & (ix1 < WW);
            float v00 = (y0ok && x0ok) ? xb[(iy0*WW+ix0)*CC + lane] : 0.f;
            float v01 = (y0ok && x1ok) ? xb[(iy0*WW+ix1)*CC + lane] : 0.f;
            float v10 = (y1ok && x0ok) ? xb[(iy1*WW+ix0)*CC + lane] : 0.f;
            float v11 = (y1ok && x1ok) ? xb[(iy1*WW+ix1)*CC + lane] : 0.f;
            float s = v00*wy0*wx0 + v01*wy0*wx1 + v10*wy1*wx0 + v11*wy1*wx1;
            samp[p][k*64 + lane] = s * m;
        }
    }
    __syncthreads();

    // ---- phase 2: out[64 x 16] = w_t^T(64x576) . samp(576x16) ----
    int p  = t & 15;
    int og = t >> 4;         // 0..15
    int o0 = og * 4;
    float acc0 = 0.f, acc1 = 0.f, acc2 = 0.f, acc3 = 0.f;
#pragma unroll 4
    for (int rq = 0; rq < 144; ++rq) {
        int r = rq * 4;
        float4 sv = *(const float4*)&samp[p][r];
        float4 w0 = *(const float4*)&wt[(r+0)*64 + o0];
        float4 w1 = *(const float4*)&wt[(r+1)*64 + o0];
        float4 w2 = *(const float4*)&wt[(r+2)*64 + o0];
        float4 w3 = *(const float4*)&wt[(r+3)*64 + o0];
        acc0 += sv.x*w0.x + sv.y*w1.x + sv.z*w2.x + sv.w*w3.x;
        acc1 += sv.x*w0.y + sv.y*w1.y + sv.z*w2.y + sv.w*w3.y;
        acc2 += sv.x*w0.z + sv.y*w1.z + sv.z*w2.z + sv.w*w3.z;
        acc3 += sv.x*w0.w + sv.y*w1.w + sv.z*w2.w + sv.w*w3.w;
    }
    float4 bv = *(const float4*)&bias[o0];
    size_t ob = (((size_t)b*COUT + o0)*HH + y)*WW + xs + p;
    out[ob]         = acc0 + bv.x;
    out[ob +   HWs] = acc1 + bv.y;
    out[ob + 2*HWs] = acc2 + bv.z;
    out[ob + 3*HWs] = acc3 + bv.w;
}

extern "C" void kernel_launch(void* const* d_in, const int* in_sizes, int n_in,
                              void* d_out, int out_size, void* d_ws, size_t ws_size,
                              hipStream_t stream) {
    const float* x      = (const float*)d_in[0];
    const float* w_off  = (const float*)d_in[1];
    const float* b_off  = (const float*)d_in[2];
    const float* w_mask = (const float*)d_in[3];
    const float* b_mask = (const float*)d_in[4];
    const float* w      = (const float*)d_in[5];
    const float* bias   = (const float*)d_in[6];
    float* out = (float*)d_out;

    char* ws = (char*)d_ws;
    float* xt = (float*)(ws);
    float* om = (float*)(ws + 16777216);
    float* wt = (float*)(ws + 16777216 + 7077888);

    hipLaunchKernelGGL(k_transpose_x, dim3(1024), dim3(256), 0, stream, x, xt);
    hipLaunchKernelGGL(k_transpose_w, dim3(144),  dim3(256), 0, stream, w, wt);
    hipLaunchKernelGGL(k_conv_om,     dim3(6912), dim3(256), 0, stream,
                       x, w_off, b_off, w_mask, b_mask, om);
    hipLaunchKernelGGL(k_main,        dim3(4096), dim3(256), 0, stream,
                       xt, om, wt, bias, out);
}

// Round 2
// 113.115 us; speedup vs baseline: 5.1256x; 5.1256x over previous
//
#include <hip/hip_runtime.h>
#include <math.h>

typedef __attribute__((ext_vector_type(8))) short short8;
typedef __attribute__((ext_vector_type(4))) float f32x4;
typedef unsigned short ushort_t;
typedef unsigned int uint_t;

#define HH 128
#define WW 128
#define CC 64
#define HWp 16384

__device__ inline ushort_t f2bf(float f) {
    uint_t u = __float_as_uint(f);
    uint_t r = (u + 0x7FFFu + ((u >> 16) & 1u)) >> 16;
    return (ushort_t)r;
}
__device__ inline float bf2f(ushort_t u) {
    return __uint_as_float(((uint_t)u) << 16);
}
__device__ inline short8 bc8(uint4 v) { return __builtin_bit_cast(short8, v); }

// ---------------- weight packing into MFMA A-fragment order -----------------
// wpom: 18 ksteps x 2 mfrag x 64 lanes x 8 bf16   (M=32 rows: 0..17 offset, 18..26 mask)
// wpm : 18 ksteps x 4 mfrag x 64 lanes x 8 bf16   (M=64 output channels)
// K index = kk*64 + c  (kk = ki*3+kj in [0,9), c = input channel)
__global__ __launch_bounds__(256) void k_pack(const float* __restrict__ w_off,
        const float* __restrict__ w_mask, const float* __restrict__ w,
        ushort_t* __restrict__ wpom, ushort_t* __restrict__ wpm) {
    int idx = blockIdx.x * 256 + threadIdx.x;
    if (idx < 18432) {
        int e = idx;
        int j = e & 7, l = (e >> 3) & 63, mf = (e >> 9) & 1, ks = e >> 10;
        int ch = mf * 16 + (l & 15);
        int k = ks * 32 + ((l >> 4) << 3) + j;
        int c = k & 63, kk = k >> 6;
        float v = 0.f;
        if (ch < 18) v = w_off[(ch * CC + c) * 9 + kk];
        else if (ch < 27) v = w_mask[((ch - 18) * CC + c) * 9 + kk];
        wpom[idx] = f2bf(v);
    } else if (idx < 18432 + 36864) {
        int e = idx - 18432;
        int j = e & 7, l = (e >> 3) & 63, mf = (e >> 9) & 3, ks = e >> 11;
        int o = mf * 16 + (l & 15);
        int k = ks * 32 + ((l >> 4) << 3) + j;
        int c = k & 63, kk = k >> 6;
        wpm[e] = f2bf(w[(o * CC + c) * 9 + kk]);
    }
}

// ---------------- x: NCHW f32 -> NHWC bf16 ----------------------------------
__global__ __launch_bounds__(256) void k_transpose_x(const float* __restrict__ x,
                                                     ushort_t* __restrict__ xtb) {
    __shared__ float tile[64][65];
    int bid = blockIdx.x;
    int xs = (bid & 1) * 64;
    int y  = (bid >> 1) & 127;
    int b  = bid >> 8;
    int t = threadIdx.x, lane = t & 63, g = t >> 6;
#pragma unroll
    for (int i = 0; i < 16; ++i) {
        int c = i * 4 + g;
        tile[c][lane] = x[(((size_t)b * CC + c) * HH + y) * WW + xs + lane];
    }
    __syncthreads();
#pragma unroll
    for (int i = 0; i < 16; ++i) {
        int xx = i * 4 + g;
        xtb[(((size_t)b * HH + y) * WW + xs + xx) * CC + lane] = f2bf(tile[lane][xx]);
    }
}

// ---------------- offset/mask conv as MFMA GEMM -----------------------------
// Per block: one (b, y). N = 128 px (row), M = 32 (27 used), K = 576.
// im2col from 3 NHWC rows staged in swizzled LDS.
__global__ __launch_bounds__(256) void k_conv_om(const ushort_t* __restrict__ xtb,
        const uint4* __restrict__ wpom, const float* __restrict__ b_off,
        const float* __restrict__ b_mask, float* __restrict__ om) {
    __shared__ ushort_t xrow[3 * 132 * 64];   // idx ^= (col&7)<<3 swizzle
    int blk = blockIdx.x;
    int y = blk & 127, b = blk >> 7;
    int t = threadIdx.x;

    for (int ky = 0; ky < 3; ++ky) {
        int yy = y + ky - 1;
        bool ok = (yy >= 0) && (yy < HH);
#pragma unroll
        for (int i = 0; i < 4; ++i) {
            int t2 = i * 256 + t;
            int colr = t2 >> 3;            // 0..127  (x coordinate)
            int c0 = (t2 & 7) * 8;
            uint4 v = make_uint4(0u, 0u, 0u, 0u);
            if (ok) v = *(const uint4*)&xtb[(((size_t)b * HWp) + yy * WW + colr) * CC + c0];
            int col = colr + 1;            // col 0 == x=-1
            int idx = ((ky * 132 + col) * 64 + c0) ^ ((col & 7) << 3);
            *(uint4*)&xrow[idx] = v;
        }
    }
    if (t < 48) {   // zero pad columns (x=-1 and x=128)
        int ky = t >> 4, cs = (t >> 3) & 1, chn = t & 7;
        int col = cs ? 129 : 0;
        int idx = ((ky * 132 + col) * 64 + chn * 8) ^ ((col & 7) << 3);
        *(uint4*)&xrow[idx] = make_uint4(0u, 0u, 0u, 0u);
    }
    __syncthreads();

    int lane = t & 63, w = t >> 6;
    int lm = lane & 15, lg = lane >> 4;
    f32x4 acc[2][2] = {};
#pragma unroll
    for (int ks = 0; ks < 18; ++ks) {
        int kk = ks >> 1;
        int kyy = kk / 3, kxx = kk % 3;
        int c0 = (ks & 1) * 32 + lg * 8;
        short8 a0 = bc8(wpom[(ks * 2 + 0) * 64 + lane]);
        short8 a1 = bc8(wpom[(ks * 2 + 1) * 64 + lane]);
#pragma unroll
        for (int nf = 0; nf < 2; ++nf) {
            int px = w * 32 + nf * 16 + lm;
            int col = px + kxx;
            int idx = ((kyy * 132 + col) * 64 + c0) ^ ((col & 7) << 3);
            short8 bf = *(const short8*)&xrow[idx];
            acc[0][nf] = __builtin_amdgcn_mfma_f32_16x16x32_bf16(a0, bf, acc[0][nf], 0, 0, 0);
            acc[1][nf] = __builtin_amdgcn_mfma_f32_16x16x32_bf16(a1, bf, acc[1][nf], 0, 0, 0);
        }
    }
#pragma unroll
    for (int mf = 0; mf < 2; ++mf)
#pragma unroll
        for (int nf = 0; nf < 2; ++nf)
#pragma unroll
            for (int r = 0; r < 4; ++r) {
                int ch = mf * 16 + lg * 4 + r;
                if (ch < 27) {
                    float v = acc[mf][nf][r] + (ch < 18 ? b_off[ch] : b_mask[ch - 18]);
                    if (ch >= 18) v = 1.f / (1.f + __expf(-v));
                    int px = w * 32 + nf * 16 + lm;
                    om[(((size_t)b * 27 + ch) << 14) + (y << 7) + px] = v;
                }
            }
}

// ---------------- fused deform-gather + main GEMM ---------------------------
// Per block: 64 px (half row). Phase 1: build 64x576 bf16 im2col tile in
// swizzled LDS (wave = pixel iter, lane = channel). Phase 2: MFMA,
// A = packed weights (global, L1-broadcast), B = LDS tile.
__global__ __launch_bounds__(256) void k_fused(const ushort_t* __restrict__ xtb,
        const float* __restrict__ om, const uint4* __restrict__ wpm,
        const float* __restrict__ bias, float* __restrict__ out) {
    extern __shared__ ushort_t sm[];          // 64*576, idx ^= (px&7)<<3
    int blk = blockIdx.x;
    int b = blk >> 8, rem = blk & 255;
    int y = rem >> 1, xs = (rem & 1) * 64;
    int t = threadIdx.x, lane = t & 63, w = t >> 6;
    const ushort_t* xb = xtb + ((size_t)b << 20);             // b*16384*64
    const float* omb = om + (((size_t)b * 27) << 14) + (y << 7);

    for (int i = 0; i < 16; ++i) {
        int px = w * 16 + i;
        int x = xs + px;
#pragma unroll
        for (int k = 0; k < 9; ++k) {
            int ki = k / 3, kj = k % 3;
            float dy = omb[((2 * k) << 14) + x];
            float dx = omb[((2 * k + 1) << 14) + x];
            float m  = omb[((18 + k) << 14) + x];
            float sy = (float)(y - 1 + ki) + dy;
            float sx = (float)(x - 1 + kj) + dx;
            float fy = floorf(sy), fx = floorf(sx);
            float wy1 = sy - fy, wx1 = sx - fx;
            float wy0 = 1.f - wy1, wx0 = 1.f - wx1;
            int iy0 = (int)fy, ix0 = (int)fx;
            int iy1 = iy0 + 1, ix1 = ix0 + 1;
            bool y0ok = (iy0 >= 0) & (iy0 < HH), y1ok = (iy1 >= 0) & (iy1 < HH);
            bool x0ok = (ix0 >= 0) & (ix0 < WW), x1ok = (ix1 >= 0) & (ix1 < WW);
            int cy0 = min(max(iy0, 0), HH - 1), cy1 = min(max(iy1, 0), HH - 1);
            int cx0 = min(max(ix0, 0), WW - 1), cx1 = min(max(ix1, 0), WW - 1);
            float w00 = (y0ok & x0ok) ? wy0 * wx0 : 0.f;
            float w01 = (y0ok & x1ok) ? wy0 * wx1 : 0.f;
            float w10 = (y1ok & x0ok) ? wy1 * wx0 : 0.f;
            float w11 = (y1ok & x1ok) ? wy1 * wx1 : 0.f;
            float v00 = bf2f(xb[((cy0 << 7) + cx0) * 64 + lane]);
            float v01 = bf2f(xb[((cy0 << 7) + cx1) * 64 + lane]);
            float v10 = bf2f(xb[((cy1 << 7) + cx0) * 64 + lane]);
            float v11 = bf2f(xb[((cy1 << 7) + cx1) * 64 + lane]);
            float s = m * (w00 * v00 + w01 * v01 + w10 * v10 + w11 * v11);
            int idx = (px * 576 + k * 64 + lane) ^ ((px & 7) << 3);
            sm[idx] = f2bf(s);
        }
    }
    __syncthreads();

    int lm = lane & 15, lg = lane >> 4;
    int px_r = w * 16 + lm;
    f32x4 acc[4] = {};
#pragma unroll
    for (int ks = 0; ks < 18; ++ks) {
        int bidx = (px_r * 576 + ks * 32 + lg * 8) ^ ((px_r & 7) << 3);
        short8 bf = *(const short8*)&sm[bidx];
#pragma unroll
        for (int mf = 0; mf < 4; ++mf) {
            short8 af = bc8(wpm[(ks * 4 + mf) * 64 + lane]);
            acc[mf] = __builtin_amdgcn_mfma_f32_16x16x32_bf16(af, bf, acc[mf], 0, 0, 0);
        }
    }
#pragma unroll
    for (int mf = 0; mf < 4; ++mf)
#pragma unroll
        for (int r = 0; r < 4; ++r) {
            int o = mf * 16 + lg * 4 + r;
            out[(((size_t)b * 64 + o) << 14) + (y << 7) + xs + px_r] = acc[mf][r] + bias[o];
        }
}

extern "C" void kernel_launch(void* const* d_in, const int* in_sizes, int n_in,
                              void* d_out, int out_size, void* d_ws, size_t ws_size,
                              hipStream_t stream) {
    const float* x      = (const float*)d_in[0];
    const float* w_off  = (const float*)d_in[1];
    const float* b_off  = (const float*)d_in[2];
    const float* w_mask = (const float*)d_in[3];
    const float* b_mask = (const float*)d_in[4];
    const float* w      = (const float*)d_in[5];
    const float* bias   = (const float*)d_in[6];
    float* out = (float*)d_out;

    char* ws = (char*)d_ws;
    ushort_t* xtb  = (ushort_t*)(ws);                    //  8,388,608 B
    float*    om   = (float*)(ws + 8388608);             //  7,077,888 B
    ushort_t* wpom = (ushort_t*)(ws + 15466496);         //     36,864 B
    ushort_t* wpm  = (ushort_t*)(ws + 15503360);         //     73,728 B

    hipLaunchKernelGGL(k_pack, dim3(216), dim3(256), 0, stream,
                       w_off, w_mask, w, wpom, wpm);
    hipLaunchKernelGGL(k_transpose_x, dim3(1024), dim3(256), 0, stream, x, xtb);
    hipLaunchKernelGGL(k_conv_om, dim3(512), dim3(256), 0, stream,
                       xtb, (const uint4*)wpom, b_off, b_mask, om);
    hipLaunchKernelGGL(k_fused, dim3(1024), dim3(256), 73728, stream,
                       xtb, om, (const uint4*)wpm, bias, out);
}

// Round 3
// 66.780 us; speedup vs baseline: 8.6819x; 1.6938x over previous
//
#include <hip/hip_runtime.h>
#include <math.h>

typedef __attribute__((ext_vector_type(8))) short short8;
typedef __attribute__((ext_vector_type(4))) float f32x4;
typedef unsigned short ushort_t;
typedef unsigned int uint_t;

#define HH 128
#define WW 128
#define CC 64
#define HWp 16384

__device__ inline ushort_t f2bf(float f) {
    uint_t u = __float_as_uint(f);
    uint_t r = (u + 0x7FFFu + ((u >> 16) & 1u)) >> 16;
    return (ushort_t)r;
}
__device__ inline float bf2f(ushort_t u) {
    return __uint_as_float(((uint_t)u) << 16);
}
__device__ inline short8 bc8(uint4 v) { return __builtin_bit_cast(short8, v); }

// ---------------- weight packing into MFMA A-fragment order -----------------
__global__ __launch_bounds__(256) void k_pack(const float* __restrict__ w_off,
        const float* __restrict__ w_mask, const float* __restrict__ w,
        ushort_t* __restrict__ wpom, ushort_t* __restrict__ wpm) {
    int idx = blockIdx.x * 256 + threadIdx.x;
    if (idx < 18432) {
        int e = idx;
        int j = e & 7, l = (e >> 3) & 63, mf = (e >> 9) & 1, ks = e >> 10;
        int ch = mf * 16 + (l & 15);
        int k = ks * 32 + ((l >> 4) << 3) + j;
        int c = k & 63, kk = k >> 6;
        float v = 0.f;
        if (ch < 18) v = w_off[(ch * CC + c) * 9 + kk];
        else if (ch < 27) v = w_mask[((ch - 18) * CC + c) * 9 + kk];
        wpom[idx] = f2bf(v);
    } else if (idx < 18432 + 36864) {
        int e = idx - 18432;
        int j = e & 7, l = (e >> 3) & 63, mf = (e >> 9) & 3, ks = e >> 11;
        int o = mf * 16 + (l & 15);
        int k = ks * 32 + ((l >> 4) << 3) + j;
        int c = k & 63, kk = k >> 6;
        wpm[e] = f2bf(w[(o * CC + c) * 9 + kk]);
    }
}

// ---------------- x: NCHW f32 -> NHWC bf16 ----------------------------------
__global__ __launch_bounds__(256) void k_transpose_x(const float* __restrict__ x,
                                                     ushort_t* __restrict__ xtb) {
    __shared__ float tile[64][65];
    int bid = blockIdx.x;
    int xs = (bid & 1) * 64;
    int y  = (bid >> 1) & 127;
    int b  = bid >> 8;
    int t = threadIdx.x, lane = t & 63, g = t >> 6;
#pragma unroll
    for (int i = 0; i < 16; ++i) {
        int c = i * 4 + g;
        tile[c][lane] = x[(((size_t)b * CC + c) * HH + y) * WW + xs + lane];
    }
    __syncthreads();
#pragma unroll
    for (int i = 0; i < 16; ++i) {
        int xx = i * 4 + g;
        xtb[(((size_t)b * HH + y) * WW + xs + xx) * CC + lane] = f2bf(tile[lane][xx]);
    }
}

// ---------------- offset/mask conv as MFMA GEMM -----------------------------
__global__ __launch_bounds__(256) void k_conv_om(const ushort_t* __restrict__ xtb,
        const uint4* __restrict__ wpom, const float* __restrict__ b_off,
        const float* __restrict__ b_mask, float* __restrict__ om) {
    __shared__ ushort_t xrow[3 * 132 * 64];   // idx ^= (col&7)<<3 swizzle
    int blk = blockIdx.x;
    int y = blk & 127, b = blk >> 7;
    int t = threadIdx.x;

    for (int ky = 0; ky < 3; ++ky) {
        int yy = y + ky - 1;
        bool ok = (yy >= 0) && (yy < HH);
#pragma unroll
        for (int i = 0; i < 4; ++i) {
            int t2 = i * 256 + t;
            int colr = t2 >> 3;
            int c0 = (t2 & 7) * 8;
            uint4 v = make_uint4(0u, 0u, 0u, 0u);
            if (ok) v = *(const uint4*)&xtb[(((size_t)b * HWp) + yy * WW + colr) * CC + c0];
            int col = colr + 1;
            int idx = ((ky * 132 + col) * 64 + c0) ^ ((col & 7) << 3);
            *(uint4*)&xrow[idx] = v;
        }
    }
    if (t < 48) {
        int ky = t >> 4, cs = (t >> 3) & 1, chn = t & 7;
        int col = cs ? 129 : 0;
        int idx = ((ky * 132 + col) * 64 + chn * 8) ^ ((col & 7) << 3);
        *(uint4*)&xrow[idx] = make_uint4(0u, 0u, 0u, 0u);
    }
    __syncthreads();

    int lane = t & 63, w = t >> 6;
    int lm = lane & 15, lg = lane >> 4;
    f32x4 acc[2][2] = {};
#pragma unroll
    for (int ks = 0; ks < 18; ++ks) {
        int kk = ks >> 1;
        int kyy = kk / 3, kxx = kk % 3;
        int c0 = (ks & 1) * 32 + lg * 8;
        short8 a0 = bc8(wpom[(ks * 2 + 0) * 64 + lane]);
        short8 a1 = bc8(wpom[(ks * 2 + 1) * 64 + lane]);
#pragma unroll
        for (int nf = 0; nf < 2; ++nf) {
            int px = w * 32 + nf * 16 + lm;
            int col = px + kxx;
            int idx = ((kyy * 132 + col) * 64 + c0) ^ ((col & 7) << 3);
            short8 bf = *(const short8*)&xrow[idx];
            acc[0][nf] = __builtin_amdgcn_mfma_f32_16x16x32_bf16(a0, bf, acc[0][nf], 0, 0, 0);
            acc[1][nf] = __builtin_amdgcn_mfma_f32_16x16x32_bf16(a1, bf, acc[1][nf], 0, 0, 0);
        }
    }
#pragma unroll
    for (int mf = 0; mf < 2; ++mf)
#pragma unroll
        for (int nf = 0; nf < 2; ++nf)
#pragma unroll
            for (int r = 0; r < 4; ++r) {
                int ch = mf * 16 + lg * 4 + r;
                if (ch < 27) {
                    float v = acc[mf][nf][r] + (ch < 18 ? b_off[ch] : b_mask[ch - 18]);
                    if (ch >= 18) v = 1.f / (1.f + __expf(-v));
                    int px = w * 32 + nf * 16 + lm;
                    om[(((size_t)b * 27 + ch) << 14) + (y << 7) + px] = v;
                }
            }
}

// ---------------- fused deform-gather + main GEMM (32 px / block) -----------
// Phase 0: 256 threads compute per-(px,k) gather params -> LDS (288 x 32B).
// Phase 1: wave = px group, lane = channel: 4 loads + 4 FMA per sample.
// Phase 2: MFMA, wave = m-frag, A = packed weights (global), B = LDS tile.
__global__ __launch_bounds__(256) void k_fused(const ushort_t* __restrict__ xtb,
        const float* __restrict__ om, const uint4* __restrict__ wpm,
        const float* __restrict__ bias, float* __restrict__ out) {
    __shared__ __align__(16) ushort_t sm[32 * 576];    // idx ^= (px&7)<<3
    __shared__ __align__(16) float prm[288][8];        // w00..w11, off00..off11
    int blk = blockIdx.x;
    int b = blk >> 9, rem = blk & 511;
    int y = rem >> 2, xs = (rem & 3) * 32;
    int t = threadIdx.x, lane = t & 63, w = t >> 6;
    const ushort_t* xb = xtb + ((size_t)b << 20);
    const float* omb = om + (((size_t)b * 27) << 14) + (y << 7) + xs;

    // ---- phase 0: per-sample params (px = s/9, k = s%9) ----
    for (int s = t; s < 288; s += 256) {
        int px = s / 9, k = s - px * 9;
        int ki = k / 3, kj = k - ki * 3;
        int x = xs + px;
        float dy = omb[((2 * k) << 14) + px];
        float dx = omb[((2 * k + 1) << 14) + px];
        float m  = omb[((18 + k) << 14) + px];
        float sy = (float)(y - 1 + ki) + dy;
        float sx = (float)(x - 1 + kj) + dx;
        float fy = floorf(sy), fx = floorf(sx);
        float wy1 = sy - fy, wx1 = sx - fx;
        float wy0 = 1.f - wy1, wx0 = 1.f - wx1;
        int iy0 = (int)fy, ix0 = (int)fx;
        int iy1 = iy0 + 1, ix1 = ix0 + 1;
        bool y0ok = (iy0 >= 0) & (iy0 < HH), y1ok = (iy1 >= 0) & (iy1 < HH);
        bool x0ok = (ix0 >= 0) & (ix0 < WW), x1ok = (ix1 >= 0) & (ix1 < WW);
        int cy0 = min(max(iy0, 0), HH - 1), cy1 = min(max(iy1, 0), HH - 1);
        int cx0 = min(max(ix0, 0), WW - 1), cx1 = min(max(ix1, 0), WW - 1);
        prm[s][0] = (y0ok & x0ok) ? m * wy0 * wx0 : 0.f;
        prm[s][1] = (y0ok & x1ok) ? m * wy0 * wx1 : 0.f;
        prm[s][2] = (y1ok & x0ok) ? m * wy1 * wx0 : 0.f;
        prm[s][3] = (y1ok & x1ok) ? m * wy1 * wx1 : 0.f;
        prm[s][4] = __uint_as_float((uint_t)(((cy0 << 7) + cx0) << 6));
        prm[s][5] = __uint_as_float((uint_t)(((cy0 << 7) + cx1) << 6));
        prm[s][6] = __uint_as_float((uint_t)(((cy1 << 7) + cx0) << 6));
        prm[s][7] = __uint_as_float((uint_t)(((cy1 << 7) + cx1) << 6));
    }
    __syncthreads();

    // ---- phase 1: gather (wave = 8 px, lane = channel) ----
    for (int i = 0; i < 8; ++i) {
        int px = w * 8 + i;
#pragma unroll
        for (int k = 0; k < 9; ++k) {
            const float* pp = prm[px * 9 + k];
            f32x4 wv = *(const f32x4*)pp;
            uint4  ov = *(const uint4*)(pp + 4);
            float v00 = bf2f(xb[ov.x + lane]);
            float v01 = bf2f(xb[ov.y + lane]);
            float v10 = bf2f(xb[ov.z + lane]);
            float v11 = bf2f(xb[ov.w + lane]);
            float s = wv.x * v00 + wv.y * v01 + wv.z * v10 + wv.w * v11;
            int idx = (px * 576 + k * 64 + lane) ^ ((px & 7) << 3);
            sm[idx] = f2bf(s);
        }
    }
    __syncthreads();

    // ---- phase 2: out[64 x 32] = W(64x576) . sm(576x32) ----
    int lm = lane & 15, lg = lane >> 4;
    f32x4 acc[2] = {};
#pragma unroll
    for (int ks = 0; ks < 18; ++ks) {
        short8 af = bc8(wpm[(ks * 4 + w) * 64 + lane]);
#pragma unroll
        for (int nf = 0; nf < 2; ++nf) {
            int px_r = nf * 16 + lm;
            int bidx = (px_r * 576 + ks * 32 + lg * 8) ^ ((px_r & 7) << 3);
            short8 bf = *(const short8*)&sm[bidx];
            acc[nf] = __builtin_amdgcn_mfma_f32_16x16x32_bf16(af, bf, acc[nf], 0, 0, 0);
        }
    }
#pragma unroll
    for (int nf = 0; nf < 2; ++nf)
#pragma unroll
        for (int r = 0; r < 4; ++r) {
            int o = w * 16 + lg * 4 + r;
            out[(((size_t)b * 64 + o) << 14) + (y << 7) + xs + nf * 16 + lm] =
                acc[nf][r] + bias[o];
        }
}

extern "C" void kernel_launch(void* const* d_in, const int* in_sizes, int n_in,
                              void* d_out, int out_size, void* d_ws, size_t ws_size,
                              hipStream_t stream) {
    const float* x      = (const float*)d_in[0];
    const float* w_off  = (const float*)d_in[1];
    const float* b_off  = (const float*)d_in[2];
    const float* w_mask = (const float*)d_in[3];
    const float* b_mask = (const float*)d_in[4];
    const float* w      = (const float*)d_in[5];
    const float* bias   = (const float*)d_in[6];
    float* out = (float*)d_out;

    char* ws = (char*)d_ws;
    ushort_t* xtb  = (ushort_t*)(ws);                    //  8,388,608 B
    float*    om   = (float*)(ws + 8388608);             //  7,077,888 B
    ushort_t* wpom = (ushort_t*)(ws + 15466496);         //     36,864 B
    ushort_t* wpm  = (ushort_t*)(ws + 15503360);         //     73,728 B

    hipLaunchKernelGGL(k_pack, dim3(216), dim3(256), 0, stream,
                       w_off, w_mask, w, wpom, wpm);
    hipLaunchKernelGGL(k_transpose_x, dim3(1024), dim3(256), 0, stream, x, xtb);
    hipLaunchKernelGGL(k_conv_om, dim3(512), dim3(256), 0, stream,
                       xtb, (const uint4*)wpom, b_off, b_mask, om);
    hipLaunchKernelGGL(k_fused, dim3(2048), dim3(256), 0, stream,
                       xtb, om, (const uint4*)wpm, bias, out);
}